// Round 19
// baseline (417.377 us; speedup 1.0000x reference)
//
#include <hip/hip_runtime.h>
#include <cstdint>
#include <cstddef>
#include <math.h>

#define SEQ   2048
#define DIM   2048
#define NQKV  6144
#define NH    16
#define DH    128
#define ROWS  4096   /* b*n */

typedef unsigned short u16;
typedef unsigned int u32;
typedef __attribute__((ext_vector_type(8))) short bf16x8;
typedef __attribute__((ext_vector_type(4))) float f32x4;
typedef __attribute__((ext_vector_type(16))) float f32x16;

__device__ __forceinline__ u16 f2bf(float f) {
  union { float f; u32 u; } v;
  v.f = f;
  u32 r = v.u + 0x7FFFu + ((v.u >> 16) & 1u);
  return (u16)(r >> 16);
}

// async global->LDS, 16B per lane; LDS dest is wave-uniform base + lane*16
__device__ __forceinline__ void gll16(const u16* g, u16* l) {
  __builtin_amdgcn_global_load_lds(
      (const __attribute__((address_space(1))) u32*)(const void*)g,
      (__attribute__((address_space(3))) u32*)(void*)l,
      16, 0, 0);
}

// --------------------- rmsnorm + bf16 cast fused (fp64 core = round-4) -----
// [VERIFIED round 18 — unchanged]
__global__ __launch_bounds__(64) void rms_bf16(
    const float* __restrict__ x, const float* __restrict__ g,
    u16* __restrict__ xnb) {
  int row = blockIdx.x, lane = threadIdx.x;
  const float* xr = x + (size_t)row * DIM;
  double ss = 0.0;
  for (int c = lane; c < DIM; c += 64) { double v = xr[c]; ss += v * v; }
  #pragma unroll
  for (int off = 32; off >= 1; off >>= 1) ss += __shfl_xor(ss, off);
  double nrm = sqrt(ss); if (nrm < 1e-12) nrm = 1e-12;
  double sc = 45.254833995939045 / nrm;   // sqrt(2048)/||x||
  u16* dst = xnb + (size_t)row * DIM;
  for (int c = lane; c < DIM; c += 64)
    dst[c] = f2bf((float)((double)xr[c] * sc * (double)g[c]));
}

// ------------------------------------------------- fp32 -> bf16 transpose ---
// [VERIFIED round 12 — unchanged; used for weights]
__global__ void transpose_f32_bf16(const float* __restrict__ in,
                                   u16* __restrict__ out, int R, int C) {
  __shared__ float tile[32][33];
  int bx = blockIdx.x * 32;   // C index
  int by = blockIdx.y * 32;   // R index
  int tx = threadIdx.x, ty = threadIdx.y;   // (32,8)
  #pragma unroll
  for (int j = 0; j < 32; j += 8)
    tile[ty + j][tx] = in[(size_t)(by + ty + j) * C + bx + tx];
  __syncthreads();
  #pragma unroll
  for (int j = 0; j < 32; j += 8)
    out[(size_t)(bx + ty + j) * R + by + tx] = f2bf(tile[tx][ty + j]);
}

// ------------------------- RoPE cos/sin table (fp64 build, fp32 store) ------
// [VERIFIED round 10 — unchanged]
__global__ __launch_bounds__(256) void rope_table(float2* __restrict__ tab) {
  int gid = blockIdx.x * 256 + threadIdx.x;   // 131072
  int p = gid & 63;
  int n = gid >> 6;
  double inv = pow(10000.0, -(double)p / 64.0);
  double ang = (double)n * inv;
  tab[gid] = make_float2((float)cos(ang), (float)sin(ang));
}

// --------------- bf16 NT GEMM, XCD-swizzled, global_load_lds staging --------
// [VERIFIED round 16 — unchanged; used for the output projection]
__global__ __launch_bounds__(256) void gemm_nt(
    const u16* __restrict__ A, const u16* __restrict__ BT,
    float* __restrict__ C, int M, int N, int K) {
  __shared__ u16 As[128 * 32];
  __shared__ u16 Bs[128 * 32];
  int nbn = N >> 7;
  int chunk = nbn >> 3;            // requires nbn % 8 == 0
  int wg = blockIdx.x;
  int xcd = wg & 7, g = wg >> 3;
  int bm = (g / chunk) * 128;
  int bn = (xcd * chunk + g % chunk) * 128;

  int tid = threadIdx.x;
  int wid = tid >> 6, lane = tid & 63;
  int wr = wid >> 1, wc = wid & 1;
  int fr = lane & 15, fq = lane >> 4;
  int srow_hi = lane >> 2;
  int scol = (lane & 3) * 8;

  f32x4 acc[4][4] = {};

  const u16* a_rd = As + (wr * 64 + fr) * 32 + fq * 8;
  const u16* b_rd = Bs + (wc * 64 + fr) * 32 + fq * 8;

  for (int k0 = 0; k0 < K; k0 += 32) {
    __syncthreads();
    #pragma unroll
    for (int i = 0; i < 2; ++i) {
      int c = wid * 2 + i;
      int row = c * 16 + srow_hi;
      gll16(A  + (size_t)(bm + row) * K + k0 + scol, As + c * 512);
      gll16(BT + (size_t)(bn + row) * K + k0 + scol, Bs + c * 512);
    }
    __syncthreads();

    bf16x8 af[4], bfr[4];
    #pragma unroll
    for (int m = 0; m < 4; ++m) af[m]  = *(const bf16x8*)(a_rd + m * 16 * 32);
    #pragma unroll
    for (int n = 0; n < 4; ++n) bfr[n] = *(const bf16x8*)(b_rd + n * 16 * 32);
    #pragma unroll
    for (int m = 0; m < 4; ++m)
      #pragma unroll
      for (int n = 0; n < 4; ++n)
        acc[m][n] = __builtin_amdgcn_mfma_f32_16x16x32_bf16(af[m], bfr[n], acc[m][n], 0, 0, 0);
  }
  #pragma unroll
  for (int m = 0; m < 4; ++m)
    #pragma unroll
    for (int n = 0; n < 4; ++n)
      #pragma unroll
      for (int r = 0; r < 4; ++r) {
        int row = bm + wr * 64 + m * 16 + fq * 4 + r;
        int col = bn + wc * 64 + n * 16 + fr;
        C[(size_t)row * N + col] = acc[m][n][r];
      }
}

// ---------- QKV GEMM with fused epilogue: cached_kv + RoPE + bf16 pack ------
// [VERIFIED round 18; only change: vbuf now bf16 (same f2bf values that
//  transpose_v_cast produced before — vT stays bit-identical)]
__global__ __launch_bounds__(256) void gemm_qkv(
    const u16* __restrict__ A, const u16* __restrict__ BT,
    float* __restrict__ cached, u16* __restrict__ qpk,
    u16* __restrict__ vbuf, const float2* __restrict__ tab) {
  const int M = ROWS, N = NQKV, K = DIM;
  __shared__ u16 As[128 * 32];
  __shared__ u16 Bs[128 * 32];
  int nbn = N >> 7;                // 48
  int chunk = nbn >> 3;            // 6
  int wg = blockIdx.x;
  int xcd = wg & 7, g = wg >> 3;
  int bm = (g / chunk) * 128;
  int bn = (xcd * chunk + g % chunk) * 128;

  int tid = threadIdx.x;
  int wid = tid >> 6, lane = tid & 63;
  int wr = wid >> 1, wc = wid & 1;
  int fr = lane & 15, fq = lane >> 4;
  int srow_hi = lane >> 2;
  int scol = (lane & 3) * 8;

  f32x4 acc[4][4] = {};

  const u16* a_rd = As + (wr * 64 + fr) * 32 + fq * 8;
  const u16* b_rd = Bs + (wc * 64 + fr) * 32 + fq * 8;

  for (int k0 = 0; k0 < K; k0 += 32) {
    __syncthreads();
    #pragma unroll
    for (int i = 0; i < 2; ++i) {
      int c = wid * 2 + i;
      int row = c * 16 + srow_hi;
      gll16(A  + (size_t)(bm + row) * K + k0 + scol, As + c * 512);
      gll16(BT + (size_t)(bn + row) * K + k0 + scol, Bs + c * 512);
    }
    __syncthreads();

    bf16x8 af[4], bfr[4];
    #pragma unroll
    for (int m = 0; m < 4; ++m) af[m]  = *(const bf16x8*)(a_rd + m * 16 * 32);
    #pragma unroll
    for (int n = 0; n < 4; ++n) bfr[n] = *(const bf16x8*)(b_rd + n * 16 * 32);
    #pragma unroll
    for (int m = 0; m < 4; ++m)
      #pragma unroll
      for (int n = 0; n < 4; ++n)
        acc[m][n] = __builtin_amdgcn_mfma_f32_16x16x32_bf16(af[m], bfr[n], acc[m][n], 0, 0, 0);
  }

  int typ = bn >> 11;              // 0=q, 1=k, 2=v (uniform per block)
  if (typ < 2) {
    #pragma unroll
    for (int m = 0; m < 4; ++m)
      #pragma unroll
      for (int nn = 0; nn < 4; ++nn)
        #pragma unroll
        for (int r = 0; r < 4; ++r) {
          int gr = bm + wr * 64 + m * 16 + fq * 4 + r;
          int gc = bn + wc * 64 + nn * 16 + fr;
          int n = gr & 2047;
          int lc = gc & 2047;
          int d = lc & 127;
          float v = acc[m][nn][r];
          float w = __shfl_xor(v, 1);     // RoPE pair partner (col^1)
          float2 cs = tab[n * 64 + (d >> 1)];
          float o = (d & 1) ? (v * cs.x + w * cs.y) : (v * cs.x - w * cs.y);
          qpk[(size_t)gr * 4096 + typ * 2048 + lc] = f2bf(o);
          if (typ == 1) {
            int b = gr >> 11, h = lc >> 7;
            cached[((size_t)(b * NH + h) * SEQ + n) * DH + d] = v;  // pre-RoPE k
          }
        }
  } else {
    #pragma unroll
    for (int m = 0; m < 4; ++m)
      #pragma unroll
      for (int nn = 0; nn < 4; ++nn)
        #pragma unroll
        for (int r = 0; r < 4; ++r) {
          int gr = bm + wr * 64 + m * 16 + fq * 4 + r;
          int gc = bn + wc * 64 + nn * 16 + fr;
          int n = gr & 2047, b = gr >> 11;
          int lc = gc - 4096;
          int d = lc & 127, h = lc >> 7;
          float v = acc[m][nn][r];
          cached[8388608 + ((size_t)(b * NH + h) * SEQ + n) * DH + d] = v;
          vbuf[(size_t)gr * 2048 + lc] = f2bf(v);
        }
  }
}

// ------------------- V transpose (bf16 -> bf16) -> vT[bh][d][n] -------------
// round-6-verified tiling; source is now bf16 vbuf (values identical to the
// f2bf the old fp32 transpose applied). [32][34] pad keeps reads conflict-free.
__global__ void transpose_v_bf16(const u16* __restrict__ vbuf,
                                 u16* __restrict__ vT) {
  int bh = blockIdx.z; int b = bh >> 4, h = bh & 15;
  int d0 = blockIdx.x * 32, n0 = blockIdx.y * 32;
  __shared__ u16 tile[32][34];
  int tx = threadIdx.x, ty = threadIdx.y;   // (32,8)
  const u16* src = vbuf + (size_t)(b * SEQ + n0) * 2048 + h * DH + d0;
  #pragma unroll
  for (int j = 0; j < 32; j += 8)
    tile[ty + j][tx] = src[(size_t)(ty + j) * 2048 + tx];
  __syncthreads();
  u16* dst = vT + ((size_t)bh * DH + d0) * SEQ + n0;
  #pragma unroll
  for (int j = 0; j < 32; j += 8)
    dst[(size_t)(ty + j) * SEQ + tx] = tile[tx][ty + j];
}

// -------- swapped-operand 32x32 MFMA causal flash attention, KV-split -------
// Round-17-verified tile body. Launch change: 2 waves per block; per phase,
// wave0 takes kv-tiles [0, ceil(n/2)), wave1 the rest (round-18 diagnosis:
// 1024 waves on 1024 SIMDs = 1 wave/SIMD, zero TLP). Each wave keeps private
// (m, l, acc); ONE LDS merge per phase: O = O_A e^{mA-m*} + O_B e^{mB-m*},
// l* = lA e^{mA-m*} + lB e^{mB-m*} — exact same math as online rescale.
// Empty wave1 range (qt=0): m=-3e38, l=0, acc=0 -> e^{mB-m*}=0, harmless.
__global__ __launch_bounds__(128) void attn_swap(
    const u16* __restrict__ qkp,   // packed post-RoPE bf16 q,k: [4096][4096]
    const u16* __restrict__ vT,    // (32,128,2048) bf16
    u16* __restrict__ ctx) {       // (4096, 2048) bf16
  int wg = blockIdx.x;             // 0..1023
  int xcd = wg & 7;
  int g   = wg >> 3;               // 0..127 within-XCD sequence
  int bh  = (g >> 5) * 8 + xcd;    // 0..31 (XCD x owns bh = x,8+x,16+x,24+x)
  int qp  = g & 31;                // pair index
  int b = bh >> 4, h = bh & 15;
  int tid = threadIdx.x;
  int wv = tid >> 6;               // wave 0 / 1
  int lane = tid & 63;
  int ln = lane & 31;
  int hi = lane >> 5;

  __shared__ float accbuf[64][65]; // wave1's acc, padded (conflict-free)
  __shared__ float mbuf[64], lbuf[64];

  const size_t rstr = 4096;        // u16 per row
  const u16* Qb = qkp + (size_t)(b * SEQ) * rstr + h * 128;
  const u16* Kb = Qb + 2048;
  const u16* Vt = vT + (size_t)bh * DH * SEQ;
  const float scale = 0.08838834764831845f;

  #pragma unroll 1
  for (int ph = 0; ph < 2; ++ph) {
    int qt = ph ? (63 - qp) : qp;
    int qr0 = qt * 32;
    int q_own = qr0 + ln;          // the query this lane's stats cover
    int ntile = qt + 1;
    int half = (ntile + 1) >> 1;   // wave0: [0,half)  wave1: [half,ntile)
    int ks0 = wv ? half : 0;
    int ks1 = wv ? ntile : half;

    bf16x8 qf[8];
    {
      const u16* qrow = Qb + (size_t)q_own * rstr + hi * 8;
      #pragma unroll
      for (int kc = 0; kc < 8; ++kc) qf[kc] = *(const bf16x8*)(qrow + kc * 16);
    }

    f32x16 acc[4] = {};            // [db] O^T accum: col=d, rows=q
    float m = -3e38f, l = 0.f;

    bf16x8 kreg[8];
    {
      const u16* krow = Kb + (size_t)(ks0 * 32 + ln) * rstr + hi * 8;
      #pragma unroll
      for (int kc = 0; kc < 8; ++kc) kreg[kc] = *(const bf16x8*)(krow + kc * 16);
    }

    for (int jt = ks0; jt < ks1; ++jt) {
      int j0 = jt * 32;

      bf16x8 vfrag[8];             // [t*4+db]: V[j0+t*16+hi*8+e][db*32+ln]
      #pragma unroll
      for (int t = 0; t < 2; ++t)
        #pragma unroll
        for (int db = 0; db < 4; ++db)
          vfrag[t * 4 + db] =
              *(const bf16x8*)(Vt + (size_t)(db * 32 + ln) * SEQ + j0 + t * 16 + hi * 8);

      // QK^T (swapped): S^T[kv][q] — two independent 4-chains, then merge
      f32x16 sacc0 = {}, sacc1 = {};
      __builtin_amdgcn_s_setprio(1);
      #pragma unroll
      for (int kc = 0; kc < 4; ++kc)
        sacc0 = __builtin_amdgcn_mfma_f32_32x32x16_bf16(kreg[kc], qf[kc], sacc0, 0, 0, 0);
      #pragma unroll
      for (int kc = 4; kc < 8; ++kc)
        sacc1 = __builtin_amdgcn_mfma_f32_32x32x16_bf16(kreg[kc], qf[kc], sacc1, 0, 0, 0);
      __builtin_amdgcn_s_setprio(0);
      f32x16 sacc = sacc0 + sacc1;

      // prefetch NEXT K tile (kreg dead after QK issues)
      if (jt + 1 < ks1) {
        const u16* krow = Kb + (size_t)(j0 + 32 + ln) * rstr + hi * 8;
        #pragma unroll
        for (int kc = 0; kc < 8; ++kc) kreg[kc] = *(const bf16x8*)(krow + kc * 16);
      }

      // mask + scale into lane-local p[16]
      float p[16];
      #pragma unroll
      for (int r = 0; r < 16; ++r) {
        int kv = j0 + (r & 3) + 8 * (r >> 2) + 4 * hi;
        float v = sacc[r] * scale;
        p[r] = (kv > q_own) ? -1e30f : v;
      }

      // lane-local max tree + one cross-half exchange
      float t8[8];
      #pragma unroll
      for (int i = 0; i < 8; ++i) t8[i] = fmaxf(p[i], p[i + 8]);
      #pragma unroll
      for (int i = 0; i < 4; ++i) t8[i] = fmaxf(t8[i], t8[i + 4]);
      float mx = fmaxf(fmaxf(t8[0], t8[1]), fmaxf(t8[2], t8[3]));
      mx = fmaxf(mx, __shfl_xor(mx, 32));

      // T13 defer-max
      if (!__all(mx - m <= 8.f)) {
        float mn = fmaxf(m, mx);
        float al = __expf(m - mn);
        m = mn;
        l *= al;
        #pragma unroll
        for (int r = 0; r < 16; ++r) {
          float alr = __shfl(al, (r & 3) + 8 * (r >> 2) + 4 * hi);
          #pragma unroll
          for (int db = 0; db < 4; ++db) acc[db][r] *= alr;
        }
      }

      // exp + lane-local sum tree + one cross-half exchange
      #pragma unroll
      for (int r = 0; r < 16; ++r) p[r] = __expf(p[r] - m);
      float s8[8];
      #pragma unroll
      for (int i = 0; i < 8; ++i) s8[i] = p[i] + p[i + 8];
      #pragma unroll
      for (int i = 0; i < 4; ++i) s8[i] = s8[i] + s8[i + 4];
      float sum = (s8[0] + s8[1]) + (s8[2] + s8[3]);
      sum += __shfl_xor(sum, 32);
      l += sum;

      // pack P to bf16 pairs, exchange halves, assemble PV A-fragments
      u32 pk[8], swk[8];
      #pragma unroll
      for (int i = 0; i < 8; ++i)
        pk[i] = (u32)f2bf(p[2 * i]) | ((u32)f2bf(p[2 * i + 1]) << 16);
      #pragma unroll
      for (int i = 0; i < 8; ++i) swk[i] = __shfl_xor(pk[i], 32);

      union { u32 w[4]; bf16x8 v; } pf0, pf1;
      pf0.w[0] = hi ? swk[2] : pk[0];
      pf0.w[1] = hi ? swk[3] : pk[1];
      pf0.w[2] = hi ? pk[2]  : swk[0];
      pf0.w[3] = hi ? pk[3]  : swk[1];
      pf1.w[0] = hi ? swk[6] : pk[4];
      pf1.w[1] = hi ? swk[7] : pk[5];
      pf1.w[2] = hi ? pk[6]  : swk[4];
      pf1.w[3] = hi ? pk[7]  : swk[5];

      // PV: O^T[q][d] += P[q][kv] * V[kv][d]
      __builtin_amdgcn_s_setprio(1);
      #pragma unroll
      for (int db = 0; db < 4; ++db) {
        acc[db] = __builtin_amdgcn_mfma_f32_32x32x16_bf16(pf0.v, vfrag[db],     acc[db], 0, 0, 0);
        acc[db] = __builtin_amdgcn_mfma_f32_32x32x16_bf16(pf1.v, vfrag[4 + db], acc[db], 0, 0, 0);
      }
      __builtin_amdgcn_s_setprio(0);
    }

    // ---- cross-wave merge (wave1 publishes; wave0 merges + stores) ----
    if (wv == 1) {
      mbuf[lane] = m;
      lbuf[lane] = l;
      #pragma unroll
      for (int db = 0; db < 4; ++db)
        #pragma unroll
        for (int r = 0; r < 16; ++r)
          accbuf[lane][db * 16 + r] = acc[db][r];
    }
    __syncthreads();
    if (wv == 0) {
      float mB = mbuf[lane], lB = lbuf[lane];
      float mM = fmaxf(m, mB);
      float eA = __expf(m - mM);
      float eB = __expf(mB - mM);
      float linv = 1.f / (l * eA + lB * eB);
      #pragma unroll
      for (int r = 0; r < 16; ++r) {
        int qrow = (r & 3) + 8 * (r >> 2) + 4 * hi;
        float eAr = __shfl(eA, qrow);
        float eBr = __shfl(eB, qrow);
        float lr  = __shfl(linv, qrow);
        int q = qr0 + qrow;
        u16* crow = ctx + (size_t)(b * SEQ + q) * DIM + h * DH + ln;
        #pragma unroll
        for (int db = 0; db < 4; ++db) {
          float o = acc[db][r] * eAr + accbuf[lane][db * 16 + r] * eBr;
          crow[db * 32] = f2bf(o * lr);
        }
      }
    }
    __syncthreads();
  }
}

// ----------------------------------------------------------------- launch ---
extern "C" void kernel_launch(void* const* d_in, const int* in_sizes, int n_in,
                              void* d_out, int out_size, void* d_ws, size_t ws_size,
                              hipStream_t stream) {
  // size-keyed input selection (sizes are pairwise distinct)
  const float *x = nullptr, *gamma = nullptr, *wq = nullptr, *wo = nullptr;
  for (int ii = 0; ii < n_in; ++ii) {
    switch (in_sizes[ii]) {
      case  8388608: x     = (const float*)d_in[ii]; break;
      case     2048: gamma = (const float*)d_in[ii]; break;
      case 12582912: wq    = (const float*)d_in[ii]; break;
      case  4194304: wo    = (const float*)d_in[ii]; break;
    }
  }
  if (!x || !gamma || !wq || !wo) {   // fallback: documented dict order
    x = (const float*)d_in[0]; gamma = (const float*)d_in[1];
    wq = (const float*)d_in[2]; wo = (const float*)d_in[3];
  }

  float* out    = (float*)d_out;           // (2,2048,2048) = first 33.55 MB
  float* cached = out + 8388608;           // (2,2,16,2048,128) at byte 33.55M

  // ws layout (exactly 128 MiB, the proven envelope):
  //   [0,       16.78M)  xnb   (bf16 A for QKV GEMM)
  //   [16.78M,  50.33M)  qpk   (packed post-RoPE bf16 q,k: [4096][4096])
  //   [50.33M,  83.89M)  vbuf  (bf16 v: [4096][2048]; region half-used)
  //   [83.89M, 109.05M)  wqkvT (bf16)
  //   [109.05M,117.44M)  woutT (bf16)
  //   [117.44M,134.22M)  ctx   (bf16)
  // out-region scratch (dead before final GEMM writes out):
  //   out[0, 16.78M)     vT (bf16)
  //   out[16.78M,17.83M) rope table
  char* ws = (char*)d_ws;
  u16*   xnb   = (u16*)ws;
  u16*   qpk   = (u16*)(ws + 16777216);
  u16*   vbuf  = (u16*)(ws + 50331648);
  u16*   wqkvT = (u16*)(ws + 83886080);
  u16*   woutT = (u16*)(ws + 109051904);
  u16*   ctx   = (u16*)(ws + 117440512);
  u16*   vT    = (u16*)d_out;
  float2* tab  = (float2*)((char*)d_out + 16777216);

  rms_bf16<<<ROWS, 64, 0, stream>>>(x, gamma, xnb);
  rope_table<<<131072 / 256, 256, 0, stream>>>(tab);
  transpose_f32_bf16<<<dim3(NQKV / 32, DIM / 32), dim3(32, 8), 0, stream>>>(wq, wqkvT, DIM, NQKV);
  transpose_f32_bf16<<<dim3(DIM / 32, DIM / 32), dim3(32, 8), 0, stream>>>(wo, woutT, DIM, DIM);
  gemm_qkv<<<(ROWS / 128) * (NQKV / 128), 256, 0, stream>>>(xnb, wqkvT, cached, qpk, vbuf, tab);
  transpose_v_bf16<<<dim3(DH / 32, SEQ / 32, 32), dim3(32, 8), 0, stream>>>(vbuf, vT);
  attn_swap<<<1024, 128, 0, stream>>>(qpk, vT, ctx);
  gemm_nt<<<(ROWS / 128) * (DIM / 128), 256, 0, stream>>>(ctx, woutT, out, ROWS, DIM, DIM);
}

// Round 20
// 383.738 us; speedup vs baseline: 1.0877x; 1.0877x over previous
//
#include <hip/hip_runtime.h>
#include <cstdint>
#include <cstddef>
#include <math.h>

#define SEQ   2048
#define DIM   2048
#define NQKV  6144
#define NH    16
#define DH    128
#define ROWS  4096   /* b*n */

typedef unsigned short u16;
typedef unsigned int u32;
typedef __attribute__((ext_vector_type(8))) short bf16x8;
typedef __attribute__((ext_vector_type(4))) float f32x4;
typedef __attribute__((ext_vector_type(16))) float f32x16;

__device__ __forceinline__ u16 f2bf(float f) {
  union { float f; u32 u; } v;
  v.f = f;
  u32 r = v.u + 0x7FFFu + ((v.u >> 16) & 1u);
  return (u16)(r >> 16);
}

// async global->LDS, 16B per lane; LDS dest is wave-uniform base + lane*16
__device__ __forceinline__ void gll16(const u16* g, u16* l) {
  __builtin_amdgcn_global_load_lds(
      (const __attribute__((address_space(1))) u32*)(const void*)g,
      (__attribute__((address_space(3))) u32*)(void*)l,
      16, 0, 0);
}

// --------------------- rmsnorm + bf16 cast fused (fp64 core = round-4) -----
// [VERIFIED round 18 — unchanged]
__global__ __launch_bounds__(64) void rms_bf16(
    const float* __restrict__ x, const float* __restrict__ g,
    u16* __restrict__ xnb) {
  int row = blockIdx.x, lane = threadIdx.x;
  const float* xr = x + (size_t)row * DIM;
  double ss = 0.0;
  for (int c = lane; c < DIM; c += 64) { double v = xr[c]; ss += v * v; }
  #pragma unroll
  for (int off = 32; off >= 1; off >>= 1) ss += __shfl_xor(ss, off);
  double nrm = sqrt(ss); if (nrm < 1e-12) nrm = 1e-12;
  double sc = 45.254833995939045 / nrm;   // sqrt(2048)/||x||
  u16* dst = xnb + (size_t)row * DIM;
  for (int c = lane; c < DIM; c += 64)
    dst[c] = f2bf((float)((double)xr[c] * sc * (double)g[c]));
}

// ------------------------------------------------- fp32 -> bf16 transpose ---
// [VERIFIED round 12 — unchanged; used for weights]
__global__ void transpose_f32_bf16(const float* __restrict__ in,
                                   u16* __restrict__ out, int R, int C) {
  __shared__ float tile[32][33];
  int bx = blockIdx.x * 32;   // C index
  int by = blockIdx.y * 32;   // R index
  int tx = threadIdx.x, ty = threadIdx.y;   // (32,8)
  #pragma unroll
  for (int j = 0; j < 32; j += 8)
    tile[ty + j][tx] = in[(size_t)(by + ty + j) * C + bx + tx];
  __syncthreads();
  #pragma unroll
  for (int j = 0; j < 32; j += 8)
    out[(size_t)(bx + ty + j) * R + by + tx] = f2bf(tile[tx][ty + j]);
}

// ------------------------- RoPE cos/sin table (fp64 build, fp32 store) ------
// [VERIFIED round 10 — unchanged]
__global__ __launch_bounds__(256) void rope_table(float2* __restrict__ tab) {
  int gid = blockIdx.x * 256 + threadIdx.x;   // 131072
  int p = gid & 63;
  int n = gid >> 6;
  double inv = pow(10000.0, -(double)p / 64.0);
  double ang = (double)n * inv;
  tab[gid] = make_float2((float)cos(ang), (float)sin(ang));
}

// --------------- bf16 NT GEMM, XCD-swizzled, global_load_lds staging --------
// [VERIFIED round 16 — unchanged; used for the output projection]
__global__ __launch_bounds__(256) void gemm_nt(
    const u16* __restrict__ A, const u16* __restrict__ BT,
    float* __restrict__ C, int M, int N, int K) {
  __shared__ u16 As[128 * 32];
  __shared__ u16 Bs[128 * 32];
  int nbn = N >> 7;
  int chunk = nbn >> 3;            // requires nbn % 8 == 0
  int wg = blockIdx.x;
  int xcd = wg & 7, g = wg >> 3;
  int bm = (g / chunk) * 128;
  int bn = (xcd * chunk + g % chunk) * 128;

  int tid = threadIdx.x;
  int wid = tid >> 6, lane = tid & 63;
  int wr = wid >> 1, wc = wid & 1;
  int fr = lane & 15, fq = lane >> 4;
  int srow_hi = lane >> 2;
  int scol = (lane & 3) * 8;

  f32x4 acc[4][4] = {};

  const u16* a_rd = As + (wr * 64 + fr) * 32 + fq * 8;
  const u16* b_rd = Bs + (wc * 64 + fr) * 32 + fq * 8;

  for (int k0 = 0; k0 < K; k0 += 32) {
    __syncthreads();
    #pragma unroll
    for (int i = 0; i < 2; ++i) {
      int c = wid * 2 + i;
      int row = c * 16 + srow_hi;
      gll16(A  + (size_t)(bm + row) * K + k0 + scol, As + c * 512);
      gll16(BT + (size_t)(bn + row) * K + k0 + scol, Bs + c * 512);
    }
    __syncthreads();

    bf16x8 af[4], bfr[4];
    #pragma unroll
    for (int m = 0; m < 4; ++m) af[m]  = *(const bf16x8*)(a_rd + m * 16 * 32);
    #pragma unroll
    for (int n = 0; n < 4; ++n) bfr[n] = *(const bf16x8*)(b_rd + n * 16 * 32);
    #pragma unroll
    for (int m = 0; m < 4; ++m)
      #pragma unroll
      for (int n = 0; n < 4; ++n)
        acc[m][n] = __builtin_amdgcn_mfma_f32_16x16x32_bf16(af[m], bfr[n], acc[m][n], 0, 0, 0);
  }
  #pragma unroll
  for (int m = 0; m < 4; ++m)
    #pragma unroll
    for (int n = 0; n < 4; ++n)
      #pragma unroll
      for (int r = 0; r < 4; ++r) {
        int row = bm + wr * 64 + m * 16 + fq * 4 + r;
        int col = bn + wc * 64 + n * 16 + fr;
        C[(size_t)row * N + col] = acc[m][n][r];
      }
}

// ---------- QKV GEMM, fused epilogue with LDS-staged coalesced stores -------
// K-loop byte-identical to round-18-verified gemm_qkv (As/Bs now live in the
// first 16KB of a 32KB shared array). Epilogue math byte-identical; the bf16
// outputs (RoPE'd q/k -> qpk, cast v -> vbuf) are staged in LDS and stored
// as 16B-per-lane coalesced int4 rows (round-19 diagnosis: direct per-element
// u16 stores were 32B-segment scatter). cached fp32 stores stay direct
// (64B segments).
__global__ __launch_bounds__(256) void gemm_qkv(
    const u16* __restrict__ A, const u16* __restrict__ BT,
    float* __restrict__ cached, u16* __restrict__ qpk,
    u16* __restrict__ vbuf, const float2* __restrict__ tab) {
  const int M = ROWS, N = NQKV, K = DIM;
  __shared__ __align__(16) u16 S[16384];   // 32KB: K-loop uses first 16KB
  u16* As = S;
  u16* Bs = S + 4096;
  int nbn = N >> 7;                // 48
  int chunk = nbn >> 3;            // 6
  int wg = blockIdx.x;
  int xcd = wg & 7, g = wg >> 3;
  int bm = (g / chunk) * 128;
  int bn = (xcd * chunk + g % chunk) * 128;

  int tid = threadIdx.x;
  int wid = tid >> 6, lane = tid & 63;
  int wr = wid >> 1, wc = wid & 1;
  int fr = lane & 15, fq = lane >> 4;
  int srow_hi = lane >> 2;
  int scol = (lane & 3) * 8;

  f32x4 acc[4][4] = {};

  const u16* a_rd = As + (wr * 64 + fr) * 32 + fq * 8;
  const u16* b_rd = Bs + (wc * 64 + fr) * 32 + fq * 8;

  for (int k0 = 0; k0 < K; k0 += 32) {
    __syncthreads();
    #pragma unroll
    for (int i = 0; i < 2; ++i) {
      int c = wid * 2 + i;
      int row = c * 16 + srow_hi;
      gll16(A  + (size_t)(bm + row) * K + k0 + scol, As + c * 512);
      gll16(BT + (size_t)(bn + row) * K + k0 + scol, Bs + c * 512);
    }
    __syncthreads();

    bf16x8 af[4], bfr[4];
    #pragma unroll
    for (int m = 0; m < 4; ++m) af[m]  = *(const bf16x8*)(a_rd + m * 16 * 32);
    #pragma unroll
    for (int n = 0; n < 4; ++n) bfr[n] = *(const bf16x8*)(b_rd + n * 16 * 32);
    #pragma unroll
    for (int m = 0; m < 4; ++m)
      #pragma unroll
      for (int n = 0; n < 4; ++n)
        acc[m][n] = __builtin_amdgcn_mfma_f32_16x16x32_bf16(af[m], bfr[n], acc[m][n], 0, 0, 0);
  }

  int typ = bn >> 11;              // 0=q, 1=k, 2=v (uniform per block)
  int lcb = bn & 2047;             // col base within the q/k/v sub-matrix
  __syncthreads();                 // all waves' final ds_reads retired

  if (typ < 2) {
    #pragma unroll
    for (int m = 0; m < 4; ++m)
      #pragma unroll
      for (int nn = 0; nn < 4; ++nn)
        #pragma unroll
        for (int r = 0; r < 4; ++r) {
          int lrow = wr * 64 + m * 16 + fq * 4 + r;
          int lcol = wc * 64 + nn * 16 + fr;
          int gr = bm + lrow;
          int n = gr & 2047;
          int lc = lcb + lcol;
          int d = lc & 127;
          float v = acc[m][nn][r];
          float w = __shfl_xor(v, 1);     // RoPE pair partner (col^1)
          float2 cs = tab[n * 64 + (d >> 1)];
          float o = (d & 1) ? (v * cs.x + w * cs.y) : (v * cs.x - w * cs.y);
          S[lrow * 128 + lcol] = f2bf(o);
          if (typ == 1) {
            int b = gr >> 11, h = lc >> 7;
            cached[((size_t)(b * NH + h) * SEQ + n) * DH + d] = v;  // pre-RoPE k
          }
        }
    __syncthreads();
    #pragma unroll
    for (int i = 0; i < 8; ++i) {
      int f = i * 256 + tid;       // 2048 int4 = 128 rows x 16 int4
      int row = f >> 4, c16 = f & 15;
      *(int4*)(qpk + (size_t)(bm + row) * 4096 + typ * 2048 + lcb + c16 * 8) =
          ((const int4*)S)[f];
    }
  } else {
    #pragma unroll
    for (int m = 0; m < 4; ++m)
      #pragma unroll
      for (int nn = 0; nn < 4; ++nn)
        #pragma unroll
        for (int r = 0; r < 4; ++r) {
          int lrow = wr * 64 + m * 16 + fq * 4 + r;
          int lcol = wc * 64 + nn * 16 + fr;
          int gr = bm + lrow;
          int n = gr & 2047, b = gr >> 11;
          int lc = lcb + lcol;
          int d = lc & 127, h = lc >> 7;
          float v = acc[m][nn][r];
          cached[8388608 + ((size_t)(b * NH + h) * SEQ + n) * DH + d] = v;
          S[lrow * 128 + lcol] = f2bf(v);
        }
    __syncthreads();
    #pragma unroll
    for (int i = 0; i < 8; ++i) {
      int f = i * 256 + tid;
      int row = f >> 4, c16 = f & 15;
      *(int4*)(vbuf + (size_t)(bm + row) * 2048 + lcb + c16 * 8) =
          ((const int4*)S)[f];
    }
  }
}

// ------------------- V transpose (bf16 -> bf16) -> vT[bh][d][n] -------------
// [VERIFIED round 19 — unchanged]
__global__ void transpose_v_bf16(const u16* __restrict__ vbuf,
                                 u16* __restrict__ vT) {
  int bh = blockIdx.z; int b = bh >> 4, h = bh & 15;
  int d0 = blockIdx.x * 32, n0 = blockIdx.y * 32;
  __shared__ u16 tile[32][34];
  int tx = threadIdx.x, ty = threadIdx.y;   // (32,8)
  const u16* src = vbuf + (size_t)(b * SEQ + n0) * 2048 + h * DH + d0;
  #pragma unroll
  for (int j = 0; j < 32; j += 8)
    tile[ty + j][tx] = src[(size_t)(ty + j) * 2048 + tx];
  __syncthreads();
  u16* dst = vT + ((size_t)bh * DH + d0) * SEQ + n0;
  #pragma unroll
  for (int j = 0; j < 32; j += 8)
    dst[(size_t)(ty + j) * SEQ + tx] = tile[tx][ty + j];
}

// -------- swapped-operand 32x32 MFMA causal flash attention, 1 wave ---------
// [VERIFIED rounds 17/18 — byte-identical; KV-split (round 19) reverted:
//  it was neutral-to-negative (merge/barrier overhead ate the TLP gain)]
__global__ __launch_bounds__(64) void attn_swap(
    const u16* __restrict__ qkp,   // packed post-RoPE bf16 q,k: [4096][4096]
    const u16* __restrict__ vT,    // (32,128,2048) bf16
    u16* __restrict__ ctx) {       // (4096, 2048) bf16
  int wg = blockIdx.x;             // 0..1023
  int xcd = wg & 7;
  int g   = wg >> 3;               // 0..127 within-XCD sequence
  int bh  = (g >> 5) * 8 + xcd;    // 0..31 (XCD x owns bh = x,8+x,16+x,24+x)
  int qp  = g & 31;                // pair index
  int b = bh >> 4, h = bh & 15;
  int lane = threadIdx.x;
  int ln = lane & 31;
  int hi = lane >> 5;

  const size_t rstr = 4096;        // u16 per row
  const u16* Qb = qkp + (size_t)(b * SEQ) * rstr + h * 128;
  const u16* Kb = Qb + 2048;
  const u16* Vt = vT + (size_t)bh * DH * SEQ;
  const float scale = 0.08838834764831845f;

  #pragma unroll 1
  for (int ph = 0; ph < 2; ++ph) {
    int qt = ph ? (63 - qp) : qp;  // (qt+1)+(64-qt) = 65 iters per wave
    int qr0 = qt * 32;
    int q_own = qr0 + ln;          // the query this lane's stats cover

    bf16x8 qf[8];
    {
      const u16* qrow = Qb + (size_t)q_own * rstr + hi * 8;
      #pragma unroll
      for (int kc = 0; kc < 8; ++kc) qf[kc] = *(const bf16x8*)(qrow + kc * 16);
    }

    f32x16 acc[4] = {};            // [db] O^T accum: col=d, rows=q
    float m = -3e38f, l = 0.f;

    bf16x8 kreg[8];
    {
      const u16* krow = Kb + (size_t)ln * rstr + hi * 8;
      #pragma unroll
      for (int kc = 0; kc < 8; ++kc) kreg[kc] = *(const bf16x8*)(krow + kc * 16);
    }

    for (int jt = 0; jt <= qt; ++jt) {
      int j0 = jt * 32;

      bf16x8 vfrag[8];             // [t*4+db]: V[j0+t*16+hi*8+e][db*32+ln]
      #pragma unroll
      for (int t = 0; t < 2; ++t)
        #pragma unroll
        for (int db = 0; db < 4; ++db)
          vfrag[t * 4 + db] =
              *(const bf16x8*)(Vt + (size_t)(db * 32 + ln) * SEQ + j0 + t * 16 + hi * 8);

      // QK^T (swapped): S^T[kv][q] — two independent 4-chains, then merge
      f32x16 sacc0 = {}, sacc1 = {};
      __builtin_amdgcn_s_setprio(1);
      #pragma unroll
      for (int kc = 0; kc < 4; ++kc)
        sacc0 = __builtin_amdgcn_mfma_f32_32x32x16_bf16(kreg[kc], qf[kc], sacc0, 0, 0, 0);
      #pragma unroll
      for (int kc = 4; kc < 8; ++kc)
        sacc1 = __builtin_amdgcn_mfma_f32_32x32x16_bf16(kreg[kc], qf[kc], sacc1, 0, 0, 0);
      __builtin_amdgcn_s_setprio(0);
      f32x16 sacc = sacc0 + sacc1;

      // prefetch NEXT K tile (kreg dead after QK issues)
      if (jt < qt) {
        const u16* krow = Kb + (size_t)(j0 + 32 + ln) * rstr + hi * 8;
        #pragma unroll
        for (int kc = 0; kc < 8; ++kc) kreg[kc] = *(const bf16x8*)(krow + kc * 16);
      }

      // mask + scale into lane-local p[16]
      float p[16];
      #pragma unroll
      for (int r = 0; r < 16; ++r) {
        int kv = j0 + (r & 3) + 8 * (r >> 2) + 4 * hi;
        float v = sacc[r] * scale;
        p[r] = (kv > q_own) ? -1e30f : v;
      }

      // lane-local max tree + one cross-half exchange
      float t8[8];
      #pragma unroll
      for (int i = 0; i < 8; ++i) t8[i] = fmaxf(p[i], p[i + 8]);
      #pragma unroll
      for (int i = 0; i < 4; ++i) t8[i] = fmaxf(t8[i], t8[i + 4]);
      float mx = fmaxf(fmaxf(t8[0], t8[1]), fmaxf(t8[2], t8[3]));
      mx = fmaxf(mx, __shfl_xor(mx, 32));

      // T13 defer-max
      if (!__all(mx - m <= 8.f)) {
        float mn = fmaxf(m, mx);
        float al = __expf(m - mn);
        m = mn;
        l *= al;
        #pragma unroll
        for (int r = 0; r < 16; ++r) {
          float alr = __shfl(al, (r & 3) + 8 * (r >> 2) + 4 * hi);
          #pragma unroll
          for (int db = 0; db < 4; ++db) acc[db][r] *= alr;
        }
      }

      // exp + lane-local sum tree + one cross-half exchange
      #pragma unroll
      for (int r = 0; r < 16; ++r) p[r] = __expf(p[r] - m);
      float s8[8];
      #pragma unroll
      for (int i = 0; i < 8; ++i) s8[i] = p[i] + p[i + 8];
      #pragma unroll
      for (int i = 0; i < 4; ++i) s8[i] = s8[i] + s8[i + 4];
      float sum = (s8[0] + s8[1]) + (s8[2] + s8[3]);
      sum += __shfl_xor(sum, 32);
      l += sum;

      // pack P to bf16 pairs, exchange halves, assemble PV A-fragments
      u32 pk[8], swk[8];
      #pragma unroll
      for (int i = 0; i < 8; ++i)
        pk[i] = (u32)f2bf(p[2 * i]) | ((u32)f2bf(p[2 * i + 1]) << 16);
      #pragma unroll
      for (int i = 0; i < 8; ++i) swk[i] = __shfl_xor(pk[i], 32);

      union { u32 w[4]; bf16x8 v; } pf0, pf1;
      pf0.w[0] = hi ? swk[2] : pk[0];
      pf0.w[1] = hi ? swk[3] : pk[1];
      pf0.w[2] = hi ? pk[2]  : swk[0];
      pf0.w[3] = hi ? pk[3]  : swk[1];
      pf1.w[0] = hi ? swk[6] : pk[4];
      pf1.w[1] = hi ? swk[7] : pk[5];
      pf1.w[2] = hi ? pk[6]  : swk[4];
      pf1.w[3] = hi ? pk[7]  : swk[5];

      // PV: O^T[q][d] += P[q][kv] * V[kv][d]
      __builtin_amdgcn_s_setprio(1);
      #pragma unroll
      for (int db = 0; db < 4; ++db) {
        acc[db] = __builtin_amdgcn_mfma_f32_32x32x16_bf16(pf0.v, vfrag[db],     acc[db], 0, 0, 0);
        acc[db] = __builtin_amdgcn_mfma_f32_32x32x16_bf16(pf1.v, vfrag[4 + db], acc[db], 0, 0, 0);
      }
      __builtin_amdgcn_s_setprio(0);
    }

    // epilogue: divide by l (broadcast per output row) and store
    float linv = 1.f / l;
    #pragma unroll
    for (int r = 0; r < 16; ++r) {
      int qrow = (r & 3) + 8 * (r >> 2) + 4 * hi;
      float lr = __shfl(linv, qrow);
      int q = qr0 + qrow;
      u16* crow = ctx + (size_t)(b * SEQ + q) * DIM + h * DH + ln;
      #pragma unroll
      for (int db = 0; db < 4; ++db)
        crow[db * 32] = f2bf(acc[db][r] * lr);
    }
  }
}

// ----------------------------------------------------------------- launch ---
extern "C" void kernel_launch(void* const* d_in, const int* in_sizes, int n_in,
                              void* d_out, int out_size, void* d_ws, size_t ws_size,
                              hipStream_t stream) {
  // size-keyed input selection (sizes are pairwise distinct)
  const float *x = nullptr, *gamma = nullptr, *wq = nullptr, *wo = nullptr;
  for (int ii = 0; ii < n_in; ++ii) {
    switch (in_sizes[ii]) {
      case  8388608: x     = (const float*)d_in[ii]; break;
      case     2048: gamma = (const float*)d_in[ii]; break;
      case 12582912: wq    = (const float*)d_in[ii]; break;
      case  4194304: wo    = (const float*)d_in[ii]; break;
    }
  }
  if (!x || !gamma || !wq || !wo) {   // fallback: documented dict order
    x = (const float*)d_in[0]; gamma = (const float*)d_in[1];
    wq = (const float*)d_in[2]; wo = (const float*)d_in[3];
  }

  float* out    = (float*)d_out;           // (2,2048,2048) = first 33.55 MB
  float* cached = out + 8388608;           // (2,2,16,2048,128) at byte 33.55M

  // ws layout (exactly 128 MiB, the proven envelope):
  //   [0,       16.78M)  xnb   (bf16 A for QKV GEMM)
  //   [16.78M,  50.33M)  qpk   (packed post-RoPE bf16 q,k: [4096][4096])
  //   [50.33M,  83.89M)  vbuf  (bf16 v: [4096][2048]; region half-used)
  //   [83.89M, 109.05M)  wqkvT (bf16)
  //   [109.05M,117.44M)  woutT (bf16)
  //   [117.44M,134.22M)  ctx   (bf16)
  // out-region scratch (dead before final GEMM writes out):
  //   out[0, 16.78M)     vT (bf16)
  //   out[16.78M,17.83M) rope table
  char* ws = (char*)d_ws;
  u16*   xnb   = (u16*)ws;
  u16*   qpk   = (u16*)(ws + 16777216);
  u16*   vbuf  = (u16*)(ws + 50331648);
  u16*   wqkvT = (u16*)(ws + 83886080);
  u16*   woutT = (u16*)(ws + 109051904);
  u16*   ctx   = (u16*)(ws + 117440512);
  u16*   vT    = (u16*)d_out;
  float2* tab  = (float2*)((char*)d_out + 16777216);

  rms_bf16<<<ROWS, 64, 0, stream>>>(x, gamma, xnb);
  rope_table<<<131072 / 256, 256, 0, stream>>>(tab);
  transpose_f32_bf16<<<dim3(NQKV / 32, DIM / 32), dim3(32, 8), 0, stream>>>(wq, wqkvT, DIM, NQKV);
  transpose_f32_bf16<<<dim3(DIM / 32, DIM / 32), dim3(32, 8), 0, stream>>>(wo, woutT, DIM, DIM);
  gemm_qkv<<<(ROWS / 128) * (NQKV / 128), 256, 0, stream>>>(xnb, wqkvT, cached, qpk, vbuf, tab);
  transpose_v_bf16<<<dim3(DH / 32, SEQ / 32, 32), dim3(32, 8), 0, stream>>>(vbuf, vT);
  attn_swap<<<1024, 64, 0, stream>>>(qpk, vT, ctx);
  gemm_nt<<<(ROWS / 128) * (DIM / 128), 256, 0, stream>>>(ctx, woutT, out, ROWS, DIM, DIM);
}